// Round 2
// baseline (490.021 us; speedup 1.0000x reference)
//
#include <hip/hip_runtime.h>

// Problem constants (from reference)
#define N_SPARSE 16
#define N_SEQ    2
#define N_DENSE  13
#define VOCAB    100000
#define EMBED    64
#define SEQ_LEN  50
#define BATCH    4096
#define N_FEAT   (N_SPARSE + N_SEQ)          // 18
#define OUT_COLS (N_FEAT * EMBED + N_DENSE)  // 1165

// Grid layout: one wave per (feature, batch) task; 4 waves per 256-thread block.
#define EMB_TASKS   (BATCH * N_FEAT)             // 73728
#define EMB_BLOCKS  (EMB_TASKS / 4)              // 18432
#define DENSE_ELEMS (BATCH * N_DENSE)            // 53248
#define DENSE_BLOCKS ((DENSE_ELEMS + 255) / 256) // 208

__global__ __launch_bounds__(256) void emb_kernel(
    const float* __restrict__ sparse_tables,  // [16,100000,64]
    const float* __restrict__ seq_tables,     // [2,100000,64]
    const float* __restrict__ dense_vals,     // [4096,13]
    const int* __restrict__ sparse_idx,       // [16,4096]
    const int* __restrict__ seq_idx,          // [2,4096,50]
    float* __restrict__ out)                  // [4096,1165]
{
    int blk = blockIdx.x;

    if (blk < EMB_BLOCKS) {
        int task = blk * 4 + (threadIdx.x >> 6);   // 0 .. EMB_TASKS-1
        int lane = threadIdx.x & 63;
        // f-major: fidx in [0,18), b in [0,4096)
        int fidx = task >> 12;          // task / BATCH  (BATCH = 4096)
        int b    = task & (BATCH - 1);  // task % BATCH
        // Seq tasks (50 row-loads each) are fidx 0..1 so they launch first;
        // sparse single-row tasks are fidx 2..17.
        if (fidx >= N_SEQ) {
            // ---- sparse feature: single-row gather, pure copy ----
            int f   = fidx - N_SEQ;                       // 0..15
            int idx = sparse_idx[f * BATCH + b];
            float v = sparse_tables[((size_t)(f * VOCAB + idx)) * EMBED + lane];
            out[(size_t)b * OUT_COLS + f * EMBED + lane] = v;
        } else {
            // ---- sequence feature: pool 50 rows ----
            int sf = fidx;  // 0 = sum pool, 1 = mean pool
            const int* ip = seq_idx + ((size_t)(sf * BATCH + b)) * SEQ_LEN;
            int myidx = (lane < SEQ_LEN) ? ip[lane] : 0;
            const float* tab = seq_tables + (size_t)sf * VOCAB * EMBED;

            float acc = 0.f;
            float cnt = 0.f;
            #pragma unroll
            for (int s = 0; s < SEQ_LEN; ++s) {
                int idx = __shfl(myidx, s);
                float fv = tab[(size_t)idx * EMBED + lane];
                acc += fv;
                cnt += (fv != 0.f) ? 1.f : 0.f;
            }
            float r = (sf == 0) ? acc : acc / (cnt + 1e-16f);
            out[(size_t)b * OUT_COLS + (N_SPARSE + sf) * EMBED + lane] = r;
        }
    } else {
        // ---- dense passthrough ----
        int e = (blk - EMB_BLOCKS) * 256 + threadIdx.x;
        if (e < DENSE_ELEMS) {
            int b = e / N_DENSE;
            int j = e - b * N_DENSE;
            out[(size_t)b * OUT_COLS + N_FEAT * EMBED + j] = dense_vals[e];
        }
    }
}

extern "C" void kernel_launch(void* const* d_in, const int* in_sizes, int n_in,
                              void* d_out, int out_size, void* d_ws, size_t ws_size,
                              hipStream_t stream) {
    const float* sparse_tables = (const float*)d_in[0];
    const float* seq_tables    = (const float*)d_in[1];
    const float* dense_vals    = (const float*)d_in[2];
    const int*   sparse_idx    = (const int*)d_in[3];
    const int*   seq_idx       = (const int*)d_in[4];
    float*       out           = (float*)d_out;

    dim3 grid(EMB_BLOCKS + DENSE_BLOCKS);
    dim3 block(256);
    emb_kernel<<<grid, block, 0, stream>>>(sparse_tables, seq_tables, dense_vals,
                                           sparse_idx, seq_idx, out);
}

// Round 3
// 481.812 us; speedup vs baseline: 1.0170x; 1.0170x over previous
//
#include <hip/hip_runtime.h>

// Problem constants (from reference)
#define N_SPARSE 16
#define N_SEQ    2
#define N_DENSE  13
#define VOCAB    100000
#define EMBED    64
#define SEQ_LEN  50
#define BATCH    4096
#define N_FEAT   (N_SPARSE + N_SEQ)          // 18
#define OUT_COLS (N_FEAT * EMBED + N_DENSE)  // 1165

// Wave-level task layout:
//  - 8192 seq waves   (one per (sf, b)): pool 50 rows via float4 group loads
//  - 4096 sb waves    (one per b): all 16 sparse rows + 13 dense vals
#define SEQ_WAVES (N_SEQ * BATCH)            // 8192
#define SB_WAVES  (BATCH)                    // 4096
#define TOT_WAVES (SEQ_WAVES + SB_WAVES)     // 12288
#define NBLOCKS   (TOT_WAVES / 4)            // 3072 blocks of 256 threads

__global__ __launch_bounds__(256) void emb_kernel(
    const float* __restrict__ sparse_tables,  // [16,100000,64]
    const float* __restrict__ seq_tables,     // [2,100000,64]
    const float* __restrict__ dense_vals,     // [4096,13]
    const int* __restrict__ sparse_idx,       // [16,4096]
    const int* __restrict__ seq_idx,          // [2,4096,50]
    float* __restrict__ out)                  // [4096,1165]
{
    const int w    = blockIdx.x * 4 + (threadIdx.x >> 6);
    const int lane = threadIdx.x & 63;
    const int g    = lane >> 4;      // lane group 0..3 (one row per group)
    const int l16  = lane & 15;      // position within group (float4 -> 64 cols)

    if (w < SEQ_WAVES) {
        // ---------------- sequence pooling: one wave per (sf, b) ----------------
        const int sf = w >> 12;               // 0 = sum pool, 1 = mean pool
        const int b  = w & (BATCH - 1);
        const int* ip = seq_idx + ((size_t)(sf * BATCH + b)) * SEQ_LEN;
        int myidx = (lane < SEQ_LEN) ? ip[lane] : 0;   // lane s holds index of row s
        const float* tab = seq_tables + (size_t)sf * VOCAB * EMBED;

        float ax = 0.f, ay = 0.f, az = 0.f, aw = 0.f;   // column sums
        float cx = 0.f, cy = 0.f, cz = 0.f, cw = 0.f;   // nonzero counts

        // 48 rows: 12 iterations x 4 rows (one per lane group), float4/lane.
        #pragma unroll
        for (int i = 0; i < 12; ++i) {
            const int row = i * 4 + g;
            const int idx = __shfl(myidx, row);
            const float4 v = *reinterpret_cast<const float4*>(
                tab + (size_t)idx * EMBED + 4 * l16);
            ax += v.x; ay += v.y; az += v.z; aw += v.w;
            cx += (v.x != 0.f) ? 1.f : 0.f;
            cy += (v.y != 0.f) ? 1.f : 0.f;
            cz += (v.z != 0.f) ? 1.f : 0.f;
            cw += (v.w != 0.f) ? 1.f : 0.f;
        }
        // remainder rows 48,49 handled by groups 0,1 (shfl done while all active)
        {
            const int row = 48 + g;
            const int idx = __shfl(myidx, (row < SEQ_LEN) ? row : 0);
            if (row < SEQ_LEN) {
                const float4 v = *reinterpret_cast<const float4*>(
                    tab + (size_t)idx * EMBED + 4 * l16);
                ax += v.x; ay += v.y; az += v.z; aw += v.w;
                cx += (v.x != 0.f) ? 1.f : 0.f;
                cy += (v.y != 0.f) ? 1.f : 0.f;
                cz += (v.z != 0.f) ? 1.f : 0.f;
                cw += (v.w != 0.f) ? 1.f : 0.f;
            }
        }

        // reduce partial sums across the 4 lane groups (xor 16, then 32)
        ax += __shfl_xor(ax, 16); ax += __shfl_xor(ax, 32);
        ay += __shfl_xor(ay, 16); ay += __shfl_xor(ay, 32);
        az += __shfl_xor(az, 16); az += __shfl_xor(az, 32);
        aw += __shfl_xor(aw, 16); aw += __shfl_xor(aw, 32);
        if (sf == 1) {  // wave-uniform branch
            cx += __shfl_xor(cx, 16); cx += __shfl_xor(cx, 32);
            cy += __shfl_xor(cy, 16); cy += __shfl_xor(cy, 32);
            cz += __shfl_xor(cz, 16); cz += __shfl_xor(cz, 32);
            cw += __shfl_xor(cw, 16); cw += __shfl_xor(cw, 32);
            ax = ax / (cx + 1e-16f);
            ay = ay / (cy + 1e-16f);
            az = az / (cz + 1e-16f);
            aw = aw / (cw + 1e-16f);
        }

        if (lane < 16) {
            float* o = out + (size_t)b * OUT_COLS + (N_SPARSE + sf) * EMBED + 4 * l16;
            o[0] = ax; o[1] = ay; o[2] = az; o[3] = aw;
        }
    } else {
        // -------- sparse gather (16 features) + dense copy: one wave per b --------
        const int b = w - SEQ_WAVES;
        // lanes 0..15 fetch the 16 feature indices, broadcast via shfl
        int myidx16 = (lane < N_SPARSE) ? sparse_idx[lane * BATCH + b] : 0;

        float4 v[4];
        #pragma unroll
        for (int i = 0; i < 4; ++i) {
            const int f   = i * 4 + g;
            const int idx = __shfl(myidx16, f);
            v[i] = *reinterpret_cast<const float4*>(
                sparse_tables + ((size_t)f * VOCAB + idx) * EMBED + 4 * l16);
        }
        float* ob = out + (size_t)b * OUT_COLS;
        #pragma unroll
        for (int i = 0; i < 4; ++i) {
            const int f = i * 4 + g;
            float* o = ob + f * EMBED + 4 * l16;
            o[0] = v[i].x; o[1] = v[i].y; o[2] = v[i].z; o[3] = v[i].w;
        }
        // dense passthrough: 13 floats per batch row
        if (lane < N_DENSE)
            ob[N_FEAT * EMBED + lane] = dense_vals[b * N_DENSE + lane];
    }
}

extern "C" void kernel_launch(void* const* d_in, const int* in_sizes, int n_in,
                              void* d_out, int out_size, void* d_ws, size_t ws_size,
                              hipStream_t stream) {
    const float* sparse_tables = (const float*)d_in[0];
    const float* seq_tables    = (const float*)d_in[1];
    const float* dense_vals    = (const float*)d_in[2];
    const int*   sparse_idx    = (const int*)d_in[3];
    const int*   seq_idx       = (const int*)d_in[4];
    float*       out           = (float*)d_out;

    emb_kernel<<<dim3(NBLOCKS), dim3(256), 0, stream>>>(
        sparse_tables, seq_tables, dense_vals, sparse_idx, seq_idx, out);
}